// Round 12
// baseline (273.124 us; speedup 1.0000x reference)
//
#include <hip/hip_runtime.h>
#include <stdint.h>

// ---- types ----
typedef __attribute__((ext_vector_type(4))) float f32x4;
typedef __attribute__((ext_vector_type(16))) float f32x16;
typedef __attribute__((ext_vector_type(8))) short s16x8;
typedef __attribute__((ext_vector_type(4))) short s16x4;
typedef __attribute__((ext_vector_type(4))) unsigned int u32x4;
typedef __attribute__((ext_vector_type(8))) _Float16 f16x8;
typedef __attribute__((ext_vector_type(4))) _Float16 f16x4;
typedef __attribute__((ext_vector_type(2))) _Float16 f16x2;

#define MFMA16(a, b, c) __builtin_amdgcn_mfma_f32_16x16x32_bf16((a), (b), (c), 0, 0, 0)
#define MFMA32H(a, b, c) __builtin_amdgcn_mfma_f32_32x32x16_f16((a), (b), (c), 0, 0, 0)

// B=2, T=8192, D=256; rows = B*T = 16384 flat.

__device__ __forceinline__ unsigned short f2bf(float f) {
  unsigned int u = __float_as_uint(f);
  u += 0x7FFFu + ((u >> 16) & 1u);  // RNE
  return (unsigned short)(u >> 16);
}
__device__ __forceinline__ float bf2f(unsigned short h) {
  return __uint_as_float(((unsigned int)h) << 16);
}
__device__ __forceinline__ unsigned pk16(float a, float b) {
  f16x2 p;
  p[0] = (_Float16)a;  // RNE
  p[1] = (_Float16)b;
  return __builtin_bit_cast(unsigned, p);
}

// async global->LDS, 16 B per lane; gptr per-lane, lptr wave-uniform base.
typedef const __attribute__((address_space(1))) void gas_void;
typedef __attribute__((address_space(3))) void las_void;
__device__ __forceinline__ void glds16(const void* g, void* l) {
  __builtin_amdgcn_global_load_lds((gas_void*)g, (las_void*)l, 16, 0, 0);
}

// ---------------- kernel 1: weight transpose + hi/lo split (bf16) -----------
// Also zeroes the attn fused-merge flags (arr[128] | rdy[128]) each launch.
__global__ void wtrans_kernel(const float* __restrict__ Wq,
                              const float* __restrict__ Wk,
                              const float* __restrict__ Wv,
                              short* __restrict__ wt,
                              int* __restrict__ flags) {
  if (blockIdx.x == 0 && threadIdx.x < 256) flags[threadIdx.x] = 0;
  int idx = blockIdx.x * 256 + threadIdx.x;   // 768 blocks * 256
  int w = idx >> 16;
  int rc = idx & 65535;
  int d = rc >> 8;
  int n = rc & 255;
  const float* Ws = (w == 0) ? Wq : ((w == 1) ? Wk : Wv);
  float v = Ws[rc];
  unsigned short hi = f2bf(v);
  unsigned short lo = f2bf(v - bf2f(hi));
  short* th = wt + w * 131072;
  th[n * 256 + d] = (short)hi;
  th[65536 + n * 256 + d] = (short)lo;
}

// ---------------- kernel 2: QKV projection (3-term bf16 MFMA) ----------------
// UNCHANGED from R5 (validated). 256 blocks x 512 thr, 64 rows/block.
__global__ __launch_bounds__(512, 2)
void qkv_kernel(const float* __restrict__ x,
                const float* __restrict__ bq,
                const float* __restrict__ bk,
                const float* __restrict__ bv,
                const short* __restrict__ wt,
                short* __restrict__ Qf, short* __restrict__ Kf,
                short* __restrict__ Vt) {
  __shared__ short X[33792];           // hi [64][264]; lo at +16896
  int tid = threadIdx.x;
  int blk = blockIdx.x;
  int r0 = blk * 64;
  int b = r0 >> 13;
  int tl0 = r0 & 8191;
#pragma unroll
  for (int i = 0; i < 8; i++) {
    int E = i * 2048 + tid * 4;
    int r = E >> 8, col = E & 255;
    f32x4 v = *(const f32x4*)(x + (size_t)(r0 + r) * 256 + col);
    s16x4 h, lo;
#pragma unroll
    for (int j = 0; j < 4; j++) {
      unsigned short hh = f2bf(v[j]);
      h[j] = (short)hh;
      lo[j] = (short)f2bf(v[j] - bf2f(hh));
    }
    *(s16x4*)&X[r * 264 + col] = h;
    *(s16x4*)&X[16896 + r * 264 + col] = lo;
  }
  __syncthreads();

  int lane = tid & 63, wv = tid >> 6;
  int quad = lane >> 4, lq = lane & 15;
  int swz8 = (quad & 1) << 3;          // bank-swizzle bit (bit6->bit3)

  // ---- Q/K: wave wv<4 -> Q col-strip wv; wv>=4 -> K col-strip wv-4 ----
  {
    int strip = wv & 3;
    bool isK = wv >= 4;
    const short* WhT = wt + (isK ? 131072 : 0);
    const short* WlT = WhT + 65536;
    f32x4 acc[4][4];
#pragma unroll
    for (int mt = 0; mt < 4; mt++)
#pragma unroll
      for (int nt = 0; nt < 4; nt++) acc[mt][nt] = (f32x4){0.f, 0.f, 0.f, 0.f};
#pragma unroll
    for (int c = 0; c < 8; c++) {
      int co = c * 32 + quad * 8;
      s16x8 wh[4], wl[4];
#pragma unroll
      for (int nt = 0; nt < 4; nt++) {
        int boff = (strip * 64 + nt * 16 + lq) * 256 + co;
        wh[nt] = *(const s16x8*)(WhT + boff);
        wl[nt] = *(const s16x8*)(WlT + boff);
      }
#pragma unroll
      for (int mt = 0; mt < 4; mt++) {
        s16x8 xh = *(const s16x8*)&X[(mt * 16 + lq) * 264 + co];
        s16x8 xl = *(const s16x8*)&X[16896 + (mt * 16 + lq) * 264 + co];
#pragma unroll
        for (int nt = 0; nt < 4; nt++) {
          acc[mt][nt] = MFMA16(xh, wh[nt], acc[mt][nt]);
          acc[mt][nt] = MFMA16(xl, wh[nt], acc[mt][nt]);
          acc[mt][nt] = MFMA16(xh, wl[nt], acc[mt][nt]);
        }
      }
    }
    const float* bias = isK ? bk : bq;
    if (!isK) {                        // Q: row-major fp16
      _Float16* Of = (_Float16*)Qf;
#pragma unroll
      for (int nt = 0; nt < 4; nt++) {
        int col = strip * 64 + nt * 16 + lq;
        float bb = bias[col];
#pragma unroll
        for (int mt = 0; mt < 4; mt++)
#pragma unroll
          for (int r = 0; r < 4; r++) {
            int row = r0 + mt * 16 + quad * 4 + r;
            Of[row * 256 + col] = (_Float16)(acc[mt][nt][r] + bb);
          }
      }
    } else {                           // K: fragment-major + swizzle
      _Float16* Of = (_Float16*)Kf;
      int kb0 = blk * 16384;           // rows r0..r0+63 share row>>6 = blk
#pragma unroll
      for (int nt = 0; nt < 4; nt++) {
        int col = strip * 64 + nt * 16 + lq;
        float bb = bias[col];
        int colpart = (col >> 4) * 1024 + ((col >> 3) & 1) * 8 + (col & 7);
#pragma unroll
        for (int mt = 0; mt < 4; mt++)
#pragma unroll
          for (int r = 0; r < 4; r++) {
            int srow = mt * 16 + quad * 4 + r;
            int idx = (kb0 + ((srow >> 5) & 1) * 512 + colpart +
                       (srow & 31) * 16) ^ swz8;
            Of[idx] = (_Float16)(acc[mt][nt][r] + bb);
          }
      }
    }
  }

  // ---- V: wave wv owns d-rows 32wv..32wv+31, all 64 s ----
  {
    const short* VhT = wt + 262144;
    const short* VlT = wt + 327680;
    f32x4 av[2][4];
#pragma unroll
    for (int sub = 0; sub < 2; sub++)
#pragma unroll
      for (int st = 0; st < 4; st++) av[sub][st] = (f32x4){0.f, 0.f, 0.f, 0.f};
#pragma unroll
    for (int c = 0; c < 8; c++) {
      int co = c * 32 + quad * 8;
      s16x8 vh[2], vl[2];
#pragma unroll
      for (int sub = 0; sub < 2; sub++) {
        int aoff = (wv * 32 + sub * 16 + lq) * 256 + co;
        vh[sub] = *(const s16x8*)(VhT + aoff);
        vl[sub] = *(const s16x8*)(VlT + aoff);
      }
#pragma unroll
      for (int st = 0; st < 4; st++) {
        s16x8 xh = *(const s16x8*)&X[(st * 16 + lq) * 264 + co];
        s16x8 xl = *(const s16x8*)&X[16896 + (st * 16 + lq) * 264 + co];
#pragma unroll
        for (int sub = 0; sub < 2; sub++) {
          av[sub][st] = MFMA16(vh[sub], xh, av[sub][st]);
          av[sub][st] = MFMA16(vl[sub], xh, av[sub][st]);
          av[sub][st] = MFMA16(vh[sub], xl, av[sub][st]);
        }
      }
    }
    _Float16* Vg = (_Float16*)Vt;
    int vbase = b * 2097152 + (tl0 >> 6) * 16384 + wv * 2048 +
                ((lq >> 3) & 1) * 8 + (lq & 7);
#pragma unroll
    for (int sub = 0; sub < 2; sub++)
#pragma unroll
      for (int r = 0; r < 4; r++) {
        int d31 = sub * 16 + quad * 4 + r;
        float bb = bv[wv * 32 + d31];
#pragma unroll
        for (int st = 0; st < 4; st++) {
          int idx = (vbase + ((st >> 1) & 1) * 1024 + (st & 1) * 512 +
                     d31 * 16) ^ swz8;
          Vg[idx] = (_Float16)(av[sub][st][r] + bb);
        }
      }
  }
}

// ---------------- kernel 3: flash attention + FUSED s-split merge -----------
// Loop = R11 (166-167us verified; attn structural floor for this decomp —
// R8/R10/R11 all null within noise; LDS-port-bound). NEW: merge_kernel is
// fused into the epilogue via last-block-done: per q-tile, the two sblk
// blocks race atomicAdd(arr[qt]). Winner ("writer") writes its partial to
// O1 + (m,l) to Mlg, fences, sets rdy[qt]. Loser ("merger") keeps its
// partial in LDS, polls rdy (safe: writer already arrived => running),
// reads writer's partial via agent-scope loads (cross-XCD coherent), and
// writes the final normalized output. Math bit-identical to merge_kernel
// (two-term FP sums commutative; own partial skips exact f32 round-trip).
__global__ __launch_bounds__(512, 2)
void attn_kernel(const short* __restrict__ Qf, const short* __restrict__ Kf,
                 const short* __restrict__ Vt,
                 float* __restrict__ out, float* __restrict__ O1,
                 float* __restrict__ Mlg, int* __restrict__ flags) {
  __shared__ short sm[81920];   // 163840 B: K0@0 K1@32768 | V@65536+32768*{0,1,2}
  int tid = threadIdx.x;
  int lane = tid & 63, wv = tid >> 6;
  int lq32 = lane & 31, hh = lane >> 5, h8 = hh * 8;
  int h8s = h8 ^ ((lq32 & 4) << 1);    // swizzled fragment byte-slot
  int strip = wv & 3, sh = wv >> 2;
  int blk = blockIdx.x;
  int qt = blk >> 1, sblk = blk & 1;
  int row0g = qt * 128;
  int b = row0g >> 13;

  // Q fragments (B-operand): q = strip*32 + lq32, k = st*16 + h8 + j
  f16x8 qf[16];
  {
    const _Float16* qrow =
        (const _Float16*)Qf + (size_t)(row0g + strip * 32 + lq32) * 256 + h8;
#pragma unroll
    for (int st = 0; st < 16; st++) qf[st] = *(const f16x8*)(qrow + st * 16);
  }
  float m_ = -__builtin_inff();        // per-lane q
  float l_ = 0.f;
  f32x16 Oacc[8];                      // O^T[d = dt*32 + row][q]
#pragma unroll
  for (int dt = 0; dt < 8; dt++)
#pragma unroll
    for (int i = 0; i < 16; i++) Oacc[dt][i] = 0.f;

  // glds bases: tile 32768 B; wave wv covers 4 KB of K and 4 KB of V.
  const char* gK = (const char*)Kf +
                   ((size_t)(b * 128 + sblk * 64) * 32768) + wv * 4096 + lane * 16;
  const char* gV = (const char*)Vt + (size_t)b * 4194304 +
                   (size_t)sblk * 2097152 + wv * 4096 + lane * 16;
  char* lds0 = (char*)sm;

  // prologue: issue tile 0 (K->kbuf0, V->vbuf0)
#pragma unroll
  for (int i = 0; i < 4; i++) {
    glds16(gK + i * 1024, lds0 + wv * 4096 + i * 1024);
    glds16(gV + i * 1024, lds0 + 65536 + wv * 4096 + i * 1024);
  }
  gK += 32768;
  gV += 32768;

  int kcur = 0;                        // byte offset of K[t]
  int vm1 = 131072, v0 = 65536, vp1 = 98304;  // V[(t-1)%3], V[t%3], V[(t+1)%3]
  f16x8 pf0p = {}, pf1p = {};          // P fragments of tile t-1

  // ---- peeled iteration 0: QK only (no PV yet) ----
  {
    __syncthreads();                   // tile 0 ready
    // issue tile 1
#pragma unroll
    for (int i = 0; i < 4; i++) {
      glds16(gK + i * 1024, lds0 + (kcur ^ 32768) + wv * 4096 + i * 1024);
      glds16(gV + i * 1024, lds0 + vp1 + wv * 4096 + i * 1024);
    }
    gK += 32768;
    gV += 32768;

    f32x16 sacc;
#pragma unroll
    for (int i = 0; i < 16; i++) sacc[i] = 0.f;
    const short* KL = (const short*)(lds0 + kcur) + sh * 512;
    __builtin_amdgcn_s_setprio(1);
#pragma unroll
    for (int st = 0; st < 16; st++) {
      f16x8 kf = *(const f16x8*)&KL[st * 1024 + lq32 * 16 + h8s];
      sacc = MFMA32H(kf, qf[st], sacc);
    }
    __builtin_amdgcn_s_setprio(0);

    float a0 = fmaxf(fmaxf(sacc[0], sacc[1]), sacc[2]);
    float a1 = fmaxf(fmaxf(sacc[3], sacc[4]), sacc[5]);
    float a2 = fmaxf(fmaxf(sacc[6], sacc[7]), sacc[8]);
    float a3 = fmaxf(fmaxf(sacc[9], sacc[10]), sacc[11]);
    float a4 = fmaxf(fmaxf(sacc[12], sacc[13]), sacc[14]);
    float b0 = fmaxf(fmaxf(a0, a1), a2);
    float b1 = fmaxf(fmaxf(a3, a4), sacc[15]);
    float mx = fmaxf(b0, b1);
    mx = fmaxf(mx, __shfl_xor(mx, 32));
    if (__any(mx > m_ + 8.f)) {
      float mn = fmaxf(m_, mx);
      float alpha = __expf(m_ - mn);
      m_ = mn;
      l_ *= alpha;
#pragma unroll
      for (int dt = 0; dt < 8; dt++) Oacc[dt] = Oacc[dt] * alpha;
    }
    float rs = 0.f;
#pragma unroll
    for (int i = 0; i < 16; i++) {
      sacc[i] = __expf(sacc[i] - m_);
      rs += sacc[i];
    }
    rs += __shfl_xor(rs, 32);
    l_ += rs;

    unsigned pa0 = pk16(sacc[0], sacc[1]), pa1 = pk16(sacc[2], sacc[3]);
    unsigned pb0 = pk16(sacc[4], sacc[5]), pb1 = pk16(sacc[6], sacc[7]);
    unsigned pc0 = pk16(sacc[8], sacc[9]), pc1 = pk16(sacc[10], sacc[11]);
    unsigned pd0 = pk16(sacc[12], sacc[13]), pd1 = pk16(sacc[14], sacc[15]);
    unsigned q0 = (unsigned)__shfl_xor((int)(hh ? pa0 : pb0), 32);
    unsigned q1 = (unsigned)__shfl_xor((int)(hh ? pa1 : pb1), 32);
    unsigned q2 = (unsigned)__shfl_xor((int)(hh ? pc0 : pd0), 32);
    unsigned q3 = (unsigned)__shfl_xor((int)(hh ? pc1 : pd1), 32);
    u32x4 P0 = hh ? (u32x4){q0, q1, pb0, pb1} : (u32x4){pa0, pa1, q0, q1};
    u32x4 P1 = hh ? (u32x4){q2, q3, pd0, pd1} : (u32x4){pc0, pc1, q2, q3};
    pf0p = __builtin_bit_cast(f16x8, P0);
    pf1p = __builtin_bit_cast(f16x8, P1);

    kcur ^= 32768;
    int tmp = vm1; vm1 = v0; v0 = vp1; vp1 = tmp;
  }

  // ---- steady state: it = 1..63, interleaved QK(it) + PV(it-1) ----
  for (int it = 1; it < 64; it++) {
    __syncthreads();                   // K[it], V[it] ready; V[it-1] intact
    if (it < 63) {                     // issue tile it+1
      int kput = kcur ^ 32768;
#pragma unroll
      for (int i = 0; i < 4; i++) {
        glds16(gK + i * 1024, lds0 + kput + wv * 4096 + i * 1024);
        glds16(gV + i * 1024, lds0 + vp1 + wv * 4096 + i * 1024);
      }
      gK += 32768;
      gV += 32768;
    }

    // interleaved MFMA block: sacc chain (QK) alternates with independent
    // Oacc updates (PV on t-1).
    f32x16 sacc;
#pragma unroll
    for (int i = 0; i < 16; i++) sacc[i] = 0.f;
    const short* KL = (const short*)(lds0 + kcur) + sh * 512;
    const short* VL = (const short*)(lds0 + vm1) + sh * 1024;
    __builtin_amdgcn_s_setprio(1);
#pragma unroll
    for (int i = 0; i < 8; i++) {
      f16x8 kfa = *(const f16x8*)&KL[(2 * i) * 1024 + lq32 * 16 + h8s];
      f16x8 kfb = *(const f16x8*)&KL[(2 * i + 1) * 1024 + lq32 * 16 + h8s];
      f16x8 vf0 = *(const f16x8*)&VL[i * 2048 + lq32 * 16 + h8s];
      f16x8 vf1 = *(const f16x8*)&VL[i * 2048 + 512 + lq32 * 16 + h8s];
      sacc = MFMA32H(kfa, qf[2 * i], sacc);
      Oacc[i] = MFMA32H(vf0, pf0p, Oacc[i]);
      sacc = MFMA32H(kfb, qf[2 * i + 1], sacc);
      Oacc[i] = MFMA32H(vf1, pf1p, Oacc[i]);
    }
    __builtin_amdgcn_s_setprio(0);

    // softmax(it): max3 tree + defer-max (THR=8)
    float a0 = fmaxf(fmaxf(sacc[0], sacc[1]), sacc[2]);
    float a1 = fmaxf(fmaxf(sacc[3], sacc[4]), sacc[5]);
    float a2 = fmaxf(fmaxf(sacc[6], sacc[7]), sacc[8]);
    float a3 = fmaxf(fmaxf(sacc[9], sacc[10]), sacc[11]);
    float a4 = fmaxf(fmaxf(sacc[12], sacc[13]), sacc[14]);
    float b0 = fmaxf(fmaxf(a0, a1), a2);
    float b1 = fmaxf(fmaxf(a3, a4), sacc[15]);
    float mx = fmaxf(b0, b1);
    mx = fmaxf(mx, __shfl_xor(mx, 32));
    if (__any(mx > m_ + 8.f)) {        // rescale only on real growth
      float mn = fmaxf(m_, mx);
      float alpha = __expf(m_ - mn);
      m_ = mn;
      l_ *= alpha;
#pragma unroll
      for (int dt = 0; dt < 8; dt++) Oacc[dt] = Oacc[dt] * alpha;
    }
    float rs = 0.f;
#pragma unroll
    for (int i = 0; i < 16; i++) {
      sacc[i] = __expf(sacc[i] - m_);
      rs += sacc[i];
    }
    rs += __shfl_xor(rs, 32);
    l_ += rs;

    // pack P(it) -> pf0p/pf1p (overwrites AFTER PV(it-1) consumed them)
    unsigned pa0 = pk16(sacc[0], sacc[1]), pa1 = pk16(sacc[2], sacc[3]);
    unsigned pb0 = pk16(sacc[4], sacc[5]), pb1 = pk16(sacc[6], sacc[7]);
    unsigned pc0 = pk16(sacc[8], sacc[9]), pc1 = pk16(sacc[10], sacc[11]);
    unsigned pd0 = pk16(sacc[12], sacc[13]), pd1 = pk16(sacc[14], sacc[15]);
    unsigned q0 = (unsigned)__shfl_xor((int)(hh ? pa0 : pb0), 32);
    unsigned q1 = (unsigned)__shfl_xor((int)(hh ? pa1 : pb1), 32);
    unsigned q2 = (unsigned)__shfl_xor((int)(hh ? pc0 : pd0), 32);
    unsigned q3 = (unsigned)__shfl_xor((int)(hh ? pc1 : pd1), 32);
    u32x4 P0 = hh ? (u32x4){q0, q1, pb0, pb1} : (u32x4){pa0, pa1, q0, q1};
    u32x4 P1 = hh ? (u32x4){q2, q3, pd0, pd1} : (u32x4){pc0, pc1, q2, q3};
    pf0p = __builtin_bit_cast(f16x8, P0);
    pf1p = __builtin_bit_cast(f16x8, P1);

    kcur ^= 32768;
    int tmp = vm1; vm1 = v0; v0 = vp1; vp1 = tmp;
  }

  // final PV(63) — V[63] is in vm1 after the last rotation
  {
    const short* VL = (const short*)(lds0 + vm1) + sh * 1024;
    __builtin_amdgcn_s_setprio(1);
#pragma unroll
    for (int dt = 0; dt < 8; dt++) {
      f16x8 vf0 = *(const f16x8*)&VL[dt * 2048 + lq32 * 16 + h8s];
      f16x8 vf1 = *(const f16x8*)&VL[dt * 2048 + 512 + lq32 * 16 + h8s];
      Oacc[dt] = MFMA32H(vf0, pf0p, Oacc[dt]);
      Oacc[dt] = MFMA32H(vf1, pf1p, Oacc[dt]);
    }
    __builtin_amdgcn_s_setprio(0);
  }
  __syncthreads();                     // all loop/final reads done before reuse

  // ---- epilogue: shalf pair-merge + fused s-split merge ----
  float* smf = (float*)sm;             // Ob: 4 strips x [32 q][132] f32
  float* Msh = smf + 16896;            // m [2][4][32], l at +256 (bytes 67584+)
  int* arr = flags;                    // arrival counters [128]
  int* rdy = flags + 128;              // ready flags [128]
  int* roleSh = (int*)(smf + 17792);   // byte 71168
  float* fA = smf + 17408;             // merger: own factor  [128]
  float* fB = smf + 17536;             // merger: other factor [128]
  float* iV = smf + 17664;             // merger: 1/l combined [128]
  if (lane < 32) {
    Msh[(sh * 4 + strip) * 32 + lq32] = m_;
    Msh[256 + (sh * 4 + strip) * 32 + lq32] = l_;
  }
  if (tid == 0) *roleSh = atomicAdd(&arr[qt], 1);
  __syncthreads();
  int role = *roleSh;
  float m1 = Msh[((1 - sh) * 4 + strip) * 32 + lq32];
  float l1 = Msh[256 + ((1 - sh) * 4 + strip) * 32 + lq32];
  float mm = fmaxf(m_, m1);
  float e0 = __expf(m_ - mm);
  float e1 = __expf(m1 - mm);
  if (role == 0) {
    // WRITER: (m,l) -> Mlg now; partial O -> O1 in the hd loop; flag at end.
    if (sh == 0 && lane < 32) {
      float lsum = l_ * e0 + l1 * e1;
      int rl = strip * 32 + lq32;
      Mlg[qt * 256 + rl * 2] = mm;
      Mlg[qt * 256 + rl * 2 + 1] = lsum;
    }
  } else {
    // MERGER: poll writer's flag, then compute per-row merge factors.
    if (tid == 0) {
      while (atomicAdd(&rdy[qt], 0) == 0) __builtin_amdgcn_s_sleep(32);
    }
    __syncthreads();
    if (sh == 0 && lane < 32) {
      int rl = strip * 32 + lq32;
      float lA = l_ * e0 + l1 * e1;
      float mB = __hip_atomic_load(&Mlg[qt * 256 + rl * 2],
                                   __ATOMIC_RELAXED, __HIP_MEMORY_SCOPE_AGENT);
      float lB = __hip_atomic_load(&Mlg[qt * 256 + rl * 2 + 1],
                                   __ATOMIC_RELAXED, __HIP_MEMORY_SCOPE_AGENT);
      float mm2 = fmaxf(mm, mB);
      float fo = __expf(mm - mm2);
      float ft = __expf(mB - mm2);
      fA[rl] = fo;
      fB[rl] = ft;
      iV[rl] = 1.f / (lA * fo + lB * ft);
    }
  }
  float* Ob = smf + strip * 4224;      // 32*132
#pragma unroll
  for (int hd = 0; hd < 2; hd++) {
    __syncthreads();
    if (sh == 1) {
#pragma unroll
      for (int dt2 = 0; dt2 < 4; dt2++) {
        int dt = hd * 4 + dt2;
#pragma unroll
        for (int g = 0; g < 4; g++) {
          f32x4 v = {Oacc[dt][g * 4], Oacc[dt][g * 4 + 1],
                     Oacc[dt][g * 4 + 2], Oacc[dt][g * 4 + 3]};
          *(f32x4*)&Ob[lq32 * 132 + dt2 * 32 + 8 * g + 4 * hh] = v;
        }
      }
    }
    __syncthreads();
    if (sh == 0) {
#pragma unroll
      for (int dt2 = 0; dt2 < 4; dt2++) {
        int dt = hd * 4 + dt2;
#pragma unroll
        for (int g = 0; g < 4; g++) {
          float* ad = &Ob[lq32 * 132 + dt2 * 32 + 8 * g + 4 * hh];
          f32x4 o1 = *(f32x4*)ad;
          f32x4 cmb;
#pragma unroll
          for (int j = 0; j < 4; j++)
            cmb[j] = Oacc[dt][g * 4 + j] * e0 + o1[j] * e1;
          *(f32x4*)ad = cmb;
        }
      }
    }
    __syncthreads();
    // cooperative coalesced write of this d-half: 128 q x 32 f32x4 groups
#pragma unroll
    for (int i = 0; i < 8; i++) {
      int idx = i * 512 + tid;
      int q = idx >> 5, gb = idx & 31;
      f32x4 v = *(f32x4*)&smf[(q >> 5) * 4224 + (q & 31) * 132 + gb * 4];
      size_t off = (size_t)(row0g + q) * 256 + hd * 128 + gb * 4;
      if (role == 0) {
        *(f32x4*)&O1[off] = v;
      } else {
        f32x4 o, r;
#pragma unroll
        for (int j = 0; j < 4; j++)
          o[j] = __hip_atomic_load(&O1[off + j], __ATOMIC_RELAXED,
                                   __HIP_MEMORY_SCOPE_AGENT);
        float fo = fA[q], ft = fB[q], iv = iV[q];
#pragma unroll
        for (int j = 0; j < 4; j++) r[j] = (v[j] * fo + o[j] * ft) * iv;
        *(f32x4*)&out[off] = r;
      }
    }
  }
  if (role == 0) {
    __syncthreads();                   // all waves' O1/Mlg stores drained
    if (tid == 0) {
      __threadfence();                 // flush XCD L2 -> device-coherent point
      atomicExch(&rdy[qt], 1);
    }
  }
}

// ---------------- launcher ----------------
extern "C" void kernel_launch(void* const* d_in, const int* in_sizes, int n_in,
                              void* d_out, int out_size, void* d_ws, size_t ws_size,
                              hipStream_t stream) {
  const float* x  = (const float*)d_in[0];
  const float* Wq = (const float*)d_in[1];
  const float* bq = (const float*)d_in[2];
  const float* Wk = (const float*)d_in[3];
  const float* bk = (const float*)d_in[4];
  const float* Wv = (const float*)d_in[5];
  const float* bv = (const float*)d_in[6];
  float* out = (float*)d_out;
  short* ws = (short*)d_ws;
  // ws layout (shorts): wt 393216 | Qf 4194304 | Kf 4194304 | Vt 4194304 |
  // O1 f32 at 12976128 (8388608 shorts) | flags (256 ints) at 21364736.
  // Mlg aliases wt (dead after qkv). Total = 42,730,496 B.
  short* wt = ws;
  short* Qf = ws + 393216;
  short* Kf = Qf + 4194304;
  short* Vt = Kf + 4194304;
  float* O1  = (float*)(ws + 12976128);
  int* flags = (int*)(ws + 21364736);
  float* Mlg = (float*)ws;
  hipLaunchKernelGGL(wtrans_kernel, dim3(768), dim3(256), 0, stream,
                     Wq, Wk, Wv, wt, flags);
  hipLaunchKernelGGL(qkv_kernel, dim3(256), dim3(512), 0, stream,
                     x, bq, bk, bv, wt, Qf, Kf, Vt);
  hipLaunchKernelGGL(attn_kernel, dim3(256), dim3(512), 0, stream,
                     Qf, Kf, Vt, out, O1, Mlg, flags);
}

// Round 13
// 256.398 us; speedup vs baseline: 1.0652x; 1.0652x over previous
//
#include <hip/hip_runtime.h>
#include <stdint.h>

// ---- types ----
typedef __attribute__((ext_vector_type(4))) float f32x4;
typedef __attribute__((ext_vector_type(16))) float f32x16;
typedef __attribute__((ext_vector_type(8))) short s16x8;
typedef __attribute__((ext_vector_type(4))) short s16x4;
typedef __attribute__((ext_vector_type(4))) unsigned int u32x4;
typedef __attribute__((ext_vector_type(8))) _Float16 f16x8;
typedef __attribute__((ext_vector_type(4))) _Float16 f16x4;
typedef __attribute__((ext_vector_type(2))) _Float16 f16x2;

#define MFMA16(a, b, c) __builtin_amdgcn_mfma_f32_16x16x32_bf16((a), (b), (c), 0, 0, 0)
#define MFMA32H(a, b, c) __builtin_amdgcn_mfma_f32_32x32x16_f16((a), (b), (c), 0, 0, 0)

// B=2, T=8192, D=256; rows = B*T = 16384 flat.

__device__ __forceinline__ unsigned short f2bf(float f) {
  unsigned int u = __float_as_uint(f);
  u += 0x7FFFu + ((u >> 16) & 1u);  // RNE
  return (unsigned short)(u >> 16);
}
__device__ __forceinline__ float bf2f(unsigned short h) {
  return __uint_as_float(((unsigned int)h) << 16);
}
__device__ __forceinline__ unsigned pk16(float a, float b) {
  f16x2 p;
  p[0] = (_Float16)a;  // RNE
  p[1] = (_Float16)b;
  return __builtin_bit_cast(unsigned, p);
}

// async global->LDS, 16 B per lane; gptr per-lane, lptr wave-uniform base.
typedef const __attribute__((address_space(1))) void gas_void;
typedef __attribute__((address_space(3))) void las_void;
__device__ __forceinline__ void glds16(const void* g, void* l) {
  __builtin_amdgcn_global_load_lds((gas_void*)g, (las_void*)l, 16, 0, 0);
}

// ---------------- kernel 1: weight transpose + hi/lo split (bf16) -----------
__global__ void wtrans_kernel(const float* __restrict__ Wq,
                              const float* __restrict__ Wk,
                              const float* __restrict__ Wv,
                              short* __restrict__ wt) {
  int idx = blockIdx.x * 256 + threadIdx.x;   // 768 blocks * 256
  int w = idx >> 16;
  int rc = idx & 65535;
  int d = rc >> 8;
  int n = rc & 255;
  const float* Ws = (w == 0) ? Wq : ((w == 1) ? Wk : Wv);
  float v = Ws[rc];
  unsigned short hi = f2bf(v);
  unsigned short lo = f2bf(v - bf2f(hi));
  short* th = wt + w * 131072;
  th[n * 256 + d] = (short)hi;
  th[65536 + n * 256 + d] = (short)lo;
}

// ---------------- kernel 2: QKV projection (3-term bf16 MFMA) ----------------
// R13: same structure/arithmetic as R5 (256 blocks x 512 thr, 64 rows/block)
// with the REGISTER-STARVATION fix: R3 profile showed VGPR_Count=68 — the
// (512,2) bounds capped VGPR at 128 and the compiler pipelined NOTHING, so
// every c-step's 16 L2 weight loads (~200-300cy) were latency-exposed at
// 2 waves/SIMD. Grid=256=1 block/CU, so (512,1) (cap 256) costs no
// occupancy; explicit c+1 weight-fragment prefetch forces the pipelining.
// Output layouts/math BIT-IDENTICAL to R5.
__global__ __launch_bounds__(512, 1)
void qkv_kernel(const float* __restrict__ x,
                const float* __restrict__ bq,
                const float* __restrict__ bk,
                const float* __restrict__ bv,
                const short* __restrict__ wt,
                short* __restrict__ Qf, short* __restrict__ Kf,
                short* __restrict__ Vt) {
  __shared__ short X[33792];           // hi [64][264]; lo at +16896
  int tid = threadIdx.x;
  int blk = blockIdx.x;
  int r0 = blk * 64;
  int b = r0 >> 13;
  int tl0 = r0 & 8191;
#pragma unroll
  for (int i = 0; i < 8; i++) {
    int E = i * 2048 + tid * 4;
    int r = E >> 8, col = E & 255;
    f32x4 v = *(const f32x4*)(x + (size_t)(r0 + r) * 256 + col);
    s16x4 h, lo;
#pragma unroll
    for (int j = 0; j < 4; j++) {
      unsigned short hh = f2bf(v[j]);
      h[j] = (short)hh;
      lo[j] = (short)f2bf(v[j] - bf2f(hh));
    }
    *(s16x4*)&X[r * 264 + col] = h;
    *(s16x4*)&X[16896 + r * 264 + col] = lo;
  }
  __syncthreads();

  int lane = tid & 63, wv = tid >> 6;
  int quad = lane >> 4, lq = lane & 15;
  int swz8 = (quad & 1) << 3;          // bank-swizzle bit (bit6->bit3)

  // ---- Q/K: wave wv<4 -> Q col-strip wv; wv>=4 -> K col-strip wv-4 ----
  {
    int strip = wv & 3;
    bool isK = wv >= 4;
    const short* WhT = wt + (isK ? 131072 : 0);
    const short* WlT = WhT + 65536;
    f32x4 acc[4][4];
#pragma unroll
    for (int mt = 0; mt < 4; mt++)
#pragma unroll
      for (int nt = 0; nt < 4; nt++) acc[mt][nt] = (f32x4){0.f, 0.f, 0.f, 0.f};
    // prefetch c=0 weight fragments
    s16x8 whc[4], wlc[4];
#pragma unroll
    for (int nt = 0; nt < 4; nt++) {
      int boff = (strip * 64 + nt * 16 + lq) * 256 + quad * 8;
      whc[nt] = *(const s16x8*)(WhT + boff);
      wlc[nt] = *(const s16x8*)(WlT + boff);
    }
#pragma unroll
    for (int c = 0; c < 8; c++) {
      int co = c * 32 + quad * 8;
      s16x8 whn[4], wln[4];
      if (c < 7) {                     // issue c+1 loads before c's MFMAs
#pragma unroll
        for (int nt = 0; nt < 4; nt++) {
          int boff = (strip * 64 + nt * 16 + lq) * 256 + co + 32;
          whn[nt] = *(const s16x8*)(WhT + boff);
          wln[nt] = *(const s16x8*)(WlT + boff);
        }
      }
#pragma unroll
      for (int mt = 0; mt < 4; mt++) {
        s16x8 xh = *(const s16x8*)&X[(mt * 16 + lq) * 264 + co];
        s16x8 xl = *(const s16x8*)&X[16896 + (mt * 16 + lq) * 264 + co];
#pragma unroll
        for (int nt = 0; nt < 4; nt++) {
          acc[mt][nt] = MFMA16(xh, whc[nt], acc[mt][nt]);
          acc[mt][nt] = MFMA16(xl, whc[nt], acc[mt][nt]);
          acc[mt][nt] = MFMA16(xh, wlc[nt], acc[mt][nt]);
        }
      }
      if (c < 7) {
#pragma unroll
        for (int nt = 0; nt < 4; nt++) { whc[nt] = whn[nt]; wlc[nt] = wln[nt]; }
      }
    }
    const float* bias = isK ? bk : bq;
    if (!isK) {                        // Q: row-major fp16
      _Float16* Of = (_Float16*)Qf;
#pragma unroll
      for (int nt = 0; nt < 4; nt++) {
        int col = strip * 64 + nt * 16 + lq;
        float bb = bias[col];
#pragma unroll
        for (int mt = 0; mt < 4; mt++)
#pragma unroll
          for (int r = 0; r < 4; r++) {
            int row = r0 + mt * 16 + quad * 4 + r;
            Of[row * 256 + col] = (_Float16)(acc[mt][nt][r] + bb);
          }
      }
    } else {                           // K: fragment-major + swizzle
      _Float16* Of = (_Float16*)Kf;
      int kb0 = blk * 16384;           // rows r0..r0+63 share row>>6 = blk
#pragma unroll
      for (int nt = 0; nt < 4; nt++) {
        int col = strip * 64 + nt * 16 + lq;
        float bb = bias[col];
        int colpart = (col >> 4) * 1024 + ((col >> 3) & 1) * 8 + (col & 7);
#pragma unroll
        for (int mt = 0; mt < 4; mt++)
#pragma unroll
          for (int r = 0; r < 4; r++) {
            int srow = mt * 16 + quad * 4 + r;
            int idx = (kb0 + ((srow >> 5) & 1) * 512 + colpart +
                       (srow & 31) * 16) ^ swz8;
            Of[idx] = (_Float16)(acc[mt][nt][r] + bb);
          }
      }
    }
  }

  // ---- V: wave wv owns d-rows 32wv..32wv+31, all 64 s ----
  {
    const short* VhT = wt + 262144;
    const short* VlT = wt + 327680;
    f32x4 av[2][4];
#pragma unroll
    for (int sub = 0; sub < 2; sub++)
#pragma unroll
      for (int st = 0; st < 4; st++) av[sub][st] = (f32x4){0.f, 0.f, 0.f, 0.f};
    s16x8 vhc[2], vlc[2];
#pragma unroll
    for (int sub = 0; sub < 2; sub++) {
      int aoff = (wv * 32 + sub * 16 + lq) * 256 + quad * 8;
      vhc[sub] = *(const s16x8*)(VhT + aoff);
      vlc[sub] = *(const s16x8*)(VlT + aoff);
    }
#pragma unroll
    for (int c = 0; c < 8; c++) {
      int co = c * 32 + quad * 8;
      s16x8 vhn[2], vln[2];
      if (c < 7) {
#pragma unroll
        for (int sub = 0; sub < 2; sub++) {
          int aoff = (wv * 32 + sub * 16 + lq) * 256 + co + 32;
          vhn[sub] = *(const s16x8*)(VhT + aoff);
          vln[sub] = *(const s16x8*)(VlT + aoff);
        }
      }
#pragma unroll
      for (int st = 0; st < 4; st++) {
        s16x8 xh = *(const s16x8*)&X[(st * 16 + lq) * 264 + co];
        s16x8 xl = *(const s16x8*)&X[16896 + (st * 16 + lq) * 264 + co];
#pragma unroll
        for (int sub = 0; sub < 2; sub++) {
          av[sub][st] = MFMA16(vhc[sub], xh, av[sub][st]);
          av[sub][st] = MFMA16(vlc[sub], xh, av[sub][st]);
          av[sub][st] = MFMA16(vhc[sub], xl, av[sub][st]);
        }
      }
      if (c < 7) {
#pragma unroll
        for (int sub = 0; sub < 2; sub++) { vhc[sub] = vhn[sub]; vlc[sub] = vln[sub]; }
      }
    }
    _Float16* Vg = (_Float16*)Vt;
    int vbase = b * 2097152 + (tl0 >> 6) * 16384 + wv * 2048 +
                ((lq >> 3) & 1) * 8 + (lq & 7);
#pragma unroll
    for (int sub = 0; sub < 2; sub++)
#pragma unroll
      for (int r = 0; r < 4; r++) {
        int d31 = sub * 16 + quad * 4 + r;
        float bb = bv[wv * 32 + d31];
#pragma unroll
        for (int st = 0; st < 4; st++) {
          int idx = (vbase + ((st >> 1) & 1) * 1024 + (st & 1) * 512 +
                     d31 * 16) ^ swz8;
          Vg[idx] = (_Float16)(av[sub][st][r] + bb);
        }
      }
  }
}

// ---------------- kernel 3: flash attention (fp16, q-block 128, 32x32) ------
// R10 attn verbatim (best verified total 256.86us; attn at its structural
// LDS-port floor — R8/R10/R11 restructures all null within noise).
// 16.78M SQ_LDS_BANK_CONFLICT is glds-intrinsic (R4/R10 falsifications).
__global__ __launch_bounds__(512, 2)
void attn_kernel(const short* __restrict__ Qf, const short* __restrict__ Kf,
                 const short* __restrict__ Vt,
                 float* __restrict__ out, float* __restrict__ O1,
                 float* __restrict__ Mlg) {
  __shared__ short sm[65792];          // 131584 B: buf{0,1} x [K 32896 | V 32896]
  int tid = threadIdx.x;
  int lane = tid & 63, wv = tid >> 6;
  int lq32 = lane & 31, hh = lane >> 5, h8 = hh * 8;
  int h8s = h8 ^ ((lq32 & 4) << 1);    // swizzled fragment byte-slot
  int strip = wv & 3, sh = wv >> 2;
  int blk = blockIdx.x;
  int qt = blk >> 1, sblk = blk & 1;
  int row0g = qt * 128;
  int b = row0g >> 13;

  // Q fragments (B-operand): q = strip*32 + lq32, k = st*16 + h8 + j
  f16x8 qf[16];
  {
    const _Float16* qrow =
        (const _Float16*)Qf + (size_t)(row0g + strip * 32 + lq32) * 256 + h8;
#pragma unroll
    for (int st = 0; st < 16; st++) qf[st] = *(const f16x8*)(qrow + st * 16);
  }
  float m_ = -__builtin_inff();        // per-lane q
  float l_ = 0.f;
  f32x16 Oacc[8];                      // O^T[d = dt*32 + row][q]
#pragma unroll
  for (int dt = 0; dt < 8; dt++)
#pragma unroll
    for (int i = 0; i < 16; i++) Oacc[dt][i] = 0.f;

  // glds bases: global tile 32768 B; wave wv covers 4 KB of K and 4 KB of V.
  // LDS dest staggered: wave chunk base wv*4112 (= wv*4096 + wv*16 pad).
  const char* gK = (const char*)Kf +
                   ((size_t)(b * 128 + sblk * 64) * 32768) + wv * 4096 + lane * 16;
  const char* gV = (const char*)Vt + (size_t)b * 4194304 +
                   (size_t)sblk * 2097152 + wv * 4096 + lane * 16;
  char* lds0 = (char*)sm;
  int wvo = wv * 4112;                 // padded per-wave LDS chunk base

  // issue tile 0 -> buf0
#pragma unroll
  for (int i = 0; i < 4; i++) {
    glds16(gK + i * 1024, lds0 + wvo + i * 1024);
    glds16(gV + i * 1024, lds0 + 32896 + wvo + i * 1024);
  }
  gK += 32768;
  gV += 32768;

  for (int it = 0; it < 64; it++) {
    int cub = it & 1;
    __syncthreads();                   // drains tile-it glds (vmcnt) + barrier
    if (it < 63) {                     // issue tile it+1 -> back buffer
      char* lb = lds0 + (cub ^ 1) * 65792;
#pragma unroll
      for (int i = 0; i < 4; i++) {
        glds16(gK + i * 1024, lb + wvo + i * 1024);
        glds16(gV + i * 1024, lb + 32896 + wvo + i * 1024);
      }
      gK += 32768;
      gV += 32768;
    }

    // S^T = K Q^T over wave's 32 s x 32 q (single-term fp16)
    // Padded reader: K row (st,sh) at st*1024 + (st>>1)*8 + sh*512 shorts.
    f32x16 sacc;
#pragma unroll
    for (int i = 0; i < 16; i++) sacc[i] = 0.f;
    const short* KL = (const short*)(lds0 + cub * 65792) + sh * 512;
    __builtin_amdgcn_s_setprio(1);
#pragma unroll
    for (int st = 0; st < 16; st++) {
      f16x8 kf = *(const f16x8*)&KL[st * 1024 + (st >> 1) * 8 + lq32 * 16 + h8s];
      sacc = MFMA32H(kf, qf[st], sacc);
    }
    __builtin_amdgcn_s_setprio(0);

    // online softmax: max3-friendly tree + defer-max (THR=8)
    float a0 = fmaxf(fmaxf(sacc[0], sacc[1]), sacc[2]);
    float a1 = fmaxf(fmaxf(sacc[3], sacc[4]), sacc[5]);
    float a2 = fmaxf(fmaxf(sacc[6], sacc[7]), sacc[8]);
    float a3 = fmaxf(fmaxf(sacc[9], sacc[10]), sacc[11]);
    float a4 = fmaxf(fmaxf(sacc[12], sacc[13]), sacc[14]);
    float b0 = fmaxf(fmaxf(a0, a1), a2);
    float b1 = fmaxf(fmaxf(a3, a4), sacc[15]);
    float mx = fmaxf(b0, b1);
    mx = fmaxf(mx, __shfl_xor(mx, 32));
    if (__any(mx > m_ + 8.f)) {        // rescale only on real growth
      float mn = fmaxf(m_, mx);
      float alpha = __expf(m_ - mn);
      m_ = mn;
      l_ *= alpha;
#pragma unroll
      for (int dt = 0; dt < 8; dt++) Oacc[dt] = Oacc[dt] * alpha;
    }
    float rs = 0.f;
#pragma unroll
    for (int i = 0; i < 16; i++) {
      sacc[i] = __expf(sacc[i] - m_);
      rs += sacc[i];
    }
    rs += __shfl_xor(rs, 32);
    l_ += rs;

    // P -> PV B-fragments fully in registers.
    // Lane (q=lq32, hh) holds s = (r&3) + 8*(r>>2) + 4*hh for r=0..15.
    unsigned pa0 = pk16(sacc[0], sacc[1]), pa1 = pk16(sacc[2], sacc[3]);
    unsigned pb0 = pk16(sacc[4], sacc[5]), pb1 = pk16(sacc[6], sacc[7]);
    unsigned pc0 = pk16(sacc[8], sacc[9]), pc1 = pk16(sacc[10], sacc[11]);
    unsigned pd0 = pk16(sacc[12], sacc[13]), pd1 = pk16(sacc[14], sacc[15]);
    unsigned q0 = (unsigned)__shfl_xor((int)(hh ? pa0 : pb0), 32);
    unsigned q1 = (unsigned)__shfl_xor((int)(hh ? pa1 : pb1), 32);
    unsigned q2 = (unsigned)__shfl_xor((int)(hh ? pc0 : pd0), 32);
    unsigned q3 = (unsigned)__shfl_xor((int)(hh ? pc1 : pd1), 32);
    u32x4 P0 = hh ? (u32x4){q0, q1, pb0, pb1} : (u32x4){pa0, pa1, q0, q1};
    u32x4 P1 = hh ? (u32x4){q2, q3, pd0, pd1} : (u32x4){pc0, pc1, q2, q3};
    f16x8 pf0 = __builtin_bit_cast(f16x8, P0);
    f16x8 pf1 = __builtin_bit_cast(f16x8, P1);

    // O^T += V P^T (A = V rows from LDS, B = P in registers)
    // Padded reader: V row group dt at dt*2056 (= dt*2048 + dt*8) shorts.
    const short* VL = (const short*)(lds0 + cub * 65792 + 32896) + sh * 1024;
    __builtin_amdgcn_s_setprio(1);
#pragma unroll
    for (int dt = 0; dt < 8; dt++) {
      f16x8 vf0 = *(const f16x8*)&VL[dt * 2056 + lq32 * 16 + h8s];
      f16x8 vf1 = *(const f16x8*)&VL[dt * 2056 + 512 + lq32 * 16 + h8s];
      Oacc[dt] = MFMA32H(vf0, pf0, Oacc[dt]);
      Oacc[dt] = MFMA32H(vf1, pf1, Oacc[dt]);
    }
    __builtin_amdgcn_s_setprio(0);
  }
  __syncthreads();                     // all loop readers done before smf reuse

  // ---- epilogue: shalf pair-merge + coalesced partial write ----
  float* smf = (float*)sm;             // Ob: 4 strips x [32 q][132] f32
  float* Msh = smf + 16896;            // m [2][4][32], l at +256
  if (lane < 32) {
    Msh[(sh * 4 + strip) * 32 + lq32] = m_;
    Msh[256 + (sh * 4 + strip) * 32 + lq32] = l_;
  }
  __syncthreads();
  float m1 = Msh[((1 - sh) * 4 + strip) * 32 + lq32];
  float l1 = Msh[256 + ((1 - sh) * 4 + strip) * 32 + lq32];
  float mm = fmaxf(m_, m1);
  float e0 = __expf(m_ - mm);
  float e1 = __expf(m1 - mm);
  float* Opart = (sblk == 0) ? out : O1;
  if (sh == 0 && lane < 32) {          // combined (m, l) for this s-block
    float lsum = l_ * e0 + l1 * e1;
    int rowq = row0g + strip * 32 + lq32;
    Mlg[sblk * 32768 + rowq * 2] = mm;
    Mlg[sblk * 32768 + rowq * 2 + 1] = lsum;
  }
  float* Ob = smf + strip * 4224;      // 32*132
#pragma unroll
  for (int hd = 0; hd < 2; hd++) {
    __syncthreads();
    if (sh == 1) {
#pragma unroll
      for (int dt2 = 0; dt2 < 4; dt2++) {
        int dt = hd * 4 + dt2;
#pragma unroll
        for (int g = 0; g < 4; g++) {
          f32x4 v = {Oacc[dt][g * 4], Oacc[dt][g * 4 + 1],
                     Oacc[dt][g * 4 + 2], Oacc[dt][g * 4 + 3]};
          *(f32x4*)&Ob[lq32 * 132 + dt2 * 32 + 8 * g + 4 * hh] = v;
        }
      }
    }
    __syncthreads();
    if (sh == 0) {
#pragma unroll
      for (int dt2 = 0; dt2 < 4; dt2++) {
        int dt = hd * 4 + dt2;
#pragma unroll
        for (int g = 0; g < 4; g++) {
          float* ad = &Ob[lq32 * 132 + dt2 * 32 + 8 * g + 4 * hh];
          f32x4 o1 = *(f32x4*)ad;
          f32x4 cmb;
#pragma unroll
          for (int j = 0; j < 4; j++)
            cmb[j] = Oacc[dt][g * 4 + j] * e0 + o1[j] * e1;
          *(f32x4*)ad = cmb;
        }
      }
    }
    __syncthreads();
    // cooperative coalesced write of this d-half: 128 q x 32 f32x4 groups
#pragma unroll
    for (int i = 0; i < 8; i++) {
      int idx = i * 512 + tid;
      int q = idx >> 5, gb = idx & 31;
      f32x4 v = *(f32x4*)&smf[(q >> 5) * 4224 + (q & 31) * 132 + gb * 4];
      *(f32x4*)&Opart[(size_t)(row0g + q) * 256 + hd * 128 + gb * 4] = v;
    }
  }
}

// ---------------- kernel 4: s-split merge ----------------
__global__ void merge_kernel(const float* __restrict__ O1,
                             const float* __restrict__ Mlg,
                             float* __restrict__ out) {
  int idx = blockIdx.x * 256 + threadIdx.x;   // 4096 blocks
  int q = idx >> 6, dg = idx & 63;
  float m0 = Mlg[q * 2], l0 = Mlg[q * 2 + 1];
  float m1 = Mlg[32768 + q * 2], l1 = Mlg[32768 + q * 2 + 1];
  float mm = fmaxf(m0, m1);
  float e0 = __expf(m0 - mm), e1 = __expf(m1 - mm);
  float inv = 1.f / (l0 * e0 + l1 * e1);
  f32x4 a = *(const f32x4*)(out + (size_t)q * 256 + dg * 4);
  f32x4 bb = *(const f32x4*)(O1 + (size_t)q * 256 + dg * 4);
  f32x4 r;
#pragma unroll
  for (int j = 0; j < 4; j++) r[j] = (a[j] * e0 + bb[j] * e1) * inv;
  *(f32x4*)(out + (size_t)q * 256 + dg * 4) = r;
}

// ---------------- launcher ----------------
extern "C" void kernel_launch(void* const* d_in, const int* in_sizes, int n_in,
                              void* d_out, int out_size, void* d_ws, size_t ws_size,
                              hipStream_t stream) {
  const float* x  = (const float*)d_in[0];
  const float* Wq = (const float*)d_in[1];
  const float* bq = (const float*)d_in[2];
  const float* Wk = (const float*)d_in[3];
  const float* bk = (const float*)d_in[4];
  const float* Wv = (const float*)d_in[5];
  const float* bv = (const float*)d_in[6];
  float* out = (float*)d_out;
  short* ws = (short*)d_ws;
  // ws layout (shorts): wt 393216 | Qf 4194304 | Kf 4194304 | Vt 4194304 |
  // O1 f32 at 12976128. Mlg aliases wt (dead after qkv).
  // Total = 42,729,472 B (validated R5/R8/R10 footprint).
  short* wt = ws;
  short* Qf = ws + 393216;
  short* Kf = Qf + 4194304;
  short* Vt = Kf + 4194304;
  float* O1  = (float*)(ws + 12976128);
  float* Mlg = (float*)ws;
  hipLaunchKernelGGL(wtrans_kernel, dim3(768), dim3(256), 0, stream, Wq, Wk, Wv, wt);
  hipLaunchKernelGGL(qkv_kernel, dim3(256), dim3(512), 0, stream,
                     x, bq, bk, bv, wt, Qf, Kf, Vt);
  hipLaunchKernelGGL(attn_kernel, dim3(256), dim3(512), 0, stream,
                     Qf, Kf, Vt, out, O1, Mlg);
  hipLaunchKernelGGL(merge_kernel, dim3(4096), dim3(256), 0, stream,
                     O1, Mlg, out);
}